// Round 9
// baseline (785.405 us; speedup 1.0000x reference)
//
#include <hip/hip_runtime.h>
#include <hip/hip_cooperative_groups.h>

namespace cg = cooperative_groups;

#define N_NODES 50000
#define DIM     128
#define E_EDGES 800000
#define ELLW    64        // ELL row stride; Poisson(16) in-degree, P(deg > 60) ~ 1e-18

typedef __attribute__((ext_vector_type(8))) short short8;
typedef __attribute__((ext_vector_type(4))) float f32x4;

__device__ __forceinline__ float bflo(unsigned int u){ return __uint_as_float(u << 16); }
__device__ __forceinline__ float bfhi(unsigned int u){ return __uint_as_float(u & 0xFFFF0000u); }
__device__ __forceinline__ unsigned int f2bf(float f){
  unsigned int u = __float_as_uint(f);
  return (u + 0x7FFFu + ((u >> 16) & 1u)) >> 16;
}
__device__ __forceinline__ unsigned int pack2(float a, float b){
  return f2bf(a) | (f2bf(b) << 16);
}

struct Params {
  const float* x; const int* edges;
  const float* lng0; const float* lnb0; const float* W0; const float* b0;
  const float* lng1; const float* lnb1; const float* W1; const float* b1;
  const float* lng2; const float* lnb2; const float* W2; const float* b2;
  int* cnt; int* epos; int2* ell; unsigned short* Wt;
  unsigned short* hn; unsigned short* yb; float* out;
};

// ---- gemm tile, M=64 (4 waves x 16 rows), bf16 A ----
__device__ __forceinline__ void gemm_tile(const unsigned short* __restrict__ A,
                                          const unsigned short* __restrict__ ldsb,
                                          unsigned short* __restrict__ Y,
                                          int base, int wave, int quad, int l15){
  int rbase = base + wave * 16;
  int rm = rbase + l15; if (rm > N_NODES - 1) rm = N_NODES - 1;
  short8 a[4];
  #pragma unroll
  for (int kk = 0; kk < 4; ++kk)
    a[kk] = *(const short8*)(A + (size_t)rm * 128 + kk * 32 + quad * 8);
  f32x4 acc[8];
  #pragma unroll
  for (int nt = 0; nt < 8; ++nt) acc[nt] = (f32x4){0.f, 0.f, 0.f, 0.f};
  #pragma unroll
  for (int kk = 0; kk < 4; ++kk)
    #pragma unroll
    for (int nt = 0; nt < 8; ++nt){
      short8 b = *(const short8*)&ldsb[(nt * 16 + l15) * 136 + kk * 32 + quad * 8];
      acc[nt] = __builtin_amdgcn_mfma_f32_16x16x32_bf16(a[kk], b, acc[nt], 0, 0, 0);
    }
  #pragma unroll
  for (int nt = 0; nt < 8; ++nt)
    #pragma unroll
    for (int r = 0; r < 4; ++r){
      int row = rbase + quad * 4 + r;
      if (row < N_NODES)
        Y[(size_t)row * 128 + nt * 16 + l15] = (unsigned short)f2bf(acc[nt][r]);
    }
}

// ---- gemm tile with fused LN+ReLU, fp32 X input ----
__device__ __forceinline__ void gemm_ln_tile(const float* __restrict__ X,
                                             const float* __restrict__ g,
                                             const float* __restrict__ bt,
                                             const unsigned short* __restrict__ ldsb,
                                             unsigned short* __restrict__ Y,
                                             int base, int wave, int quad, int l15){
  int rbase = base + wave * 16;
  int rm = rbase + l15; if (rm > N_NODES - 1) rm = N_NODES - 1;
  float v[4][8];
  float s = 0.f, ss = 0.f;
  #pragma unroll
  for (int kk = 0; kk < 4; ++kk){
    float4 xa = *(const float4*)(X + (size_t)rm * 128 + kk * 32 + quad * 8);
    float4 xb = *(const float4*)(X + (size_t)rm * 128 + kk * 32 + quad * 8 + 4);
    v[kk][0]=xa.x; v[kk][1]=xa.y; v[kk][2]=xa.z; v[kk][3]=xa.w;
    v[kk][4]=xb.x; v[kk][5]=xb.y; v[kk][6]=xb.z; v[kk][7]=xb.w;
    #pragma unroll
    for (int j = 0; j < 8; ++j){ s += v[kk][j]; ss += v[kk][j] * v[kk][j]; }
  }
  s += __shfl_xor(s, 16, 64); ss += __shfl_xor(ss, 16, 64);
  s += __shfl_xor(s, 32, 64); ss += __shfl_xor(ss, 32, 64);
  float mu = s * (1.0f/128.0f), var = ss * (1.0f/128.0f) - mu * mu;
  float rs = rsqrtf(var + 1e-5f);
  short8 a[4];
  #pragma unroll
  for (int kk = 0; kk < 4; ++kk){
    float4 ga = *(const float4*)(g  + kk * 32 + quad * 8);
    float4 gb = *(const float4*)(g  + kk * 32 + quad * 8 + 4);
    float4 ba = *(const float4*)(bt + kk * 32 + quad * 8);
    float4 bb = *(const float4*)(bt + kk * 32 + quad * 8 + 4);
    float gg[8]  = {ga.x,ga.y,ga.z,ga.w,gb.x,gb.y,gb.z,gb.w};
    float bbv[8] = {ba.x,ba.y,ba.z,ba.w,bb.x,bb.y,bb.z,bb.w};
    #pragma unroll
    for (int j = 0; j < 8; ++j){
      float h = fmaxf((v[kk][j] - mu) * rs * gg[j] + bbv[j], 0.0f);
      a[kk][j] = (short)f2bf(h);
    }
  }
  f32x4 acc[8];
  #pragma unroll
  for (int nt = 0; nt < 8; ++nt) acc[nt] = (f32x4){0.f, 0.f, 0.f, 0.f};
  #pragma unroll
  for (int kk = 0; kk < 4; ++kk)
    #pragma unroll
    for (int nt = 0; nt < 8; ++nt){
      short8 b = *(const short8*)&ldsb[(nt * 16 + l15) * 136 + kk * 32 + quad * 8];
      acc[nt] = __builtin_amdgcn_mfma_f32_16x16x32_bf16(a[kk], b, acc[nt], 0, 0, 0);
    }
  #pragma unroll
  for (int nt = 0; nt < 8; ++nt)
    #pragma unroll
    for (int r = 0; r < 4; ++r){
      int row = rbase + quad * 4 + r;
      if (row < N_NODES)
        Y[(size_t)row * 128 + nt * 16 + l15] = (unsigned short)f2bf(acc[nt][r]);
    }
}

// ---- agg phase: 4 nodes/wave, uint4 gathers, grid-stride over 3125 units ----
template<bool HAS_RES, bool DO_LN>
__device__ __forceinline__ void agg_phase(const Params& P,
                                          const unsigned short* __restrict__ y,
                                          const float* __restrict__ bias,
                                          const float* __restrict__ res,
                                          float* __restrict__ outp,
                                          const float* __restrict__ lng,
                                          const float* __restrict__ lnb,
                                          unsigned short* __restrict__ hn_out,
                                          int GB){
  int tid = threadIdx.x, lane = tid & 63, wave = tid >> 6;
  int hl = lane & 15, selbase = lane & 48;
  const uint4* y4 = (const uint4*)y;
  for (int u = blockIdx.x; u < 3125; u += GB){
    int node = u * 16 + wave * 4 + (lane >> 4);   // < 50000 exactly
    int deg = P.cnt[node];
    float di = rsqrtf((float)(deg + 1));
    float ws = di * di;

    const int2* row = P.ell + (size_t)node * ELLW;
    int2 e0 = row[hl], e1 = row[hl + 16], e2 = row[hl + 32], e3 = row[hl + 48];

    int J = deg;
    J = max(J, __shfl_xor(J, 16, 64));
    J = max(J, __shfl_xor(J, 32, 64));

    uint4 us = y4[(size_t)node * 16 + hl];
    float acc0 = ws * bflo(us.x), acc1 = ws * bfhi(us.x);
    float acc2 = ws * bflo(us.y), acc3 = ws * bfhi(us.y);
    float acc4 = ws * bflo(us.z), acc5 = ws * bfhi(us.z);
    float acc6 = ws * bflo(us.w), acc7 = ws * bfhi(us.w);

    auto block16 = [&](int2 ee, int base16){
      int rem = J - base16;
      if (rem <= 0) return;
      int nch = (min(rem, 16) + 3) >> 2;
      for (int c = 0; c < nch; ++c){
        int rb = c * 4;
        int sA = __shfl(ee.x, selbase | (rb + 0), 64);
        int sB = __shfl(ee.x, selbase | (rb + 1), 64);
        int sC = __shfl(ee.x, selbase | (rb + 2), 64);
        int sD = __shfl(ee.x, selbase | (rb + 3), 64);
        float wA = __uint_as_float((unsigned)__shfl(ee.y, selbase | (rb + 0), 64));
        float wB = __uint_as_float((unsigned)__shfl(ee.y, selbase | (rb + 1), 64));
        float wC = __uint_as_float((unsigned)__shfl(ee.y, selbase | (rb + 2), 64));
        float wD = __uint_as_float((unsigned)__shfl(ee.y, selbase | (rb + 3), 64));
        uint4 gA = y4[(size_t)sA * 16 + hl];
        uint4 gB = y4[(size_t)sB * 16 + hl];
        uint4 gC = y4[(size_t)sC * 16 + hl];
        uint4 gD = y4[(size_t)sD * 16 + hl];
        acc0 += wA*bflo(gA.x); acc1 += wA*bfhi(gA.x); acc2 += wA*bflo(gA.y); acc3 += wA*bfhi(gA.y);
        acc4 += wA*bflo(gA.z); acc5 += wA*bfhi(gA.z); acc6 += wA*bflo(gA.w); acc7 += wA*bfhi(gA.w);
        acc0 += wB*bflo(gB.x); acc1 += wB*bfhi(gB.x); acc2 += wB*bflo(gB.y); acc3 += wB*bfhi(gB.y);
        acc4 += wB*bflo(gB.z); acc5 += wB*bfhi(gB.z); acc6 += wB*bflo(gB.w); acc7 += wB*bfhi(gB.w);
        acc0 += wC*bflo(gC.x); acc1 += wC*bfhi(gC.x); acc2 += wC*bflo(gC.y); acc3 += wC*bfhi(gC.y);
        acc4 += wC*bflo(gC.z); acc5 += wC*bfhi(gC.z); acc6 += wC*bflo(gC.w); acc7 += wC*bfhi(gC.w);
        acc0 += wD*bflo(gD.x); acc1 += wD*bfhi(gD.x); acc2 += wD*bflo(gD.y); acc3 += wD*bfhi(gD.y);
        acc4 += wD*bflo(gD.z); acc5 += wD*bfhi(gD.z); acc6 += wD*bflo(gD.w); acc7 += wD*bfhi(gD.w);
      }
    };
    block16(e0, 0); block16(e1, 16); block16(e2, 32); block16(e3, 48);

    float4 ubA = ((const float4*)bias)[hl * 2];
    float4 ubB = ((const float4*)bias)[hl * 2 + 1];
    acc0 += ubA.x; acc1 += ubA.y; acc2 += ubA.z; acc3 += ubA.w;
    acc4 += ubB.x; acc5 += ubB.y; acc6 += ubB.z; acc7 += ubB.w;
    if (HAS_RES){
      float4 urA = ((const float4*)res)[(size_t)node * 32 + hl * 2];
      float4 urB = ((const float4*)res)[(size_t)node * 32 + hl * 2 + 1];
      acc0 += urA.x; acc1 += urA.y; acc2 += urA.z; acc3 += urA.w;
      acc4 += urB.x; acc5 += urB.y; acc6 += urB.z; acc7 += urB.w;
    }
    if (outp){
      float4 oA; oA.x = acc0; oA.y = acc1; oA.z = acc2; oA.w = acc3;
      float4 oB; oB.x = acc4; oB.y = acc5; oB.z = acc6; oB.w = acc7;
      ((float4*)outp)[(size_t)node * 32 + hl * 2]     = oA;
      ((float4*)outp)[(size_t)node * 32 + hl * 2 + 1] = oB;
    }
    if (DO_LN){
      float s  = acc0 + acc1 + acc2 + acc3 + acc4 + acc5 + acc6 + acc7;
      float ss = acc0*acc0 + acc1*acc1 + acc2*acc2 + acc3*acc3
               + acc4*acc4 + acc5*acc5 + acc6*acc6 + acc7*acc7;
      #pragma unroll
      for (int d = 8; d >= 1; d >>= 1){ s += __shfl_xor(s, d, 64); ss += __shfl_xor(ss, d, 64); }
      float mu  = s * (1.0f / 128.0f);
      float var = ss * (1.0f / 128.0f) - mu * mu;
      float rs  = rsqrtf(var + 1e-5f);
      float4 ugA = ((const float4*)lng)[hl * 2];
      float4 ugB = ((const float4*)lng)[hl * 2 + 1];
      float4 ubbA = ((const float4*)lnb)[hl * 2];
      float4 ubbB = ((const float4*)lnb)[hl * 2 + 1];
      float h0 = fmaxf((acc0 - mu) * rs * ugA.x + ubbA.x, 0.0f);
      float h1 = fmaxf((acc1 - mu) * rs * ugA.y + ubbA.y, 0.0f);
      float h2 = fmaxf((acc2 - mu) * rs * ugA.z + ubbA.z, 0.0f);
      float h3 = fmaxf((acc3 - mu) * rs * ugA.w + ubbA.w, 0.0f);
      float h4 = fmaxf((acc4 - mu) * rs * ugB.x + ubbB.x, 0.0f);
      float h5 = fmaxf((acc5 - mu) * rs * ugB.y + ubbB.y, 0.0f);
      float h6 = fmaxf((acc6 - mu) * rs * ugB.z + ubbB.z, 0.0f);
      float h7 = fmaxf((acc7 - mu) * rs * ugB.w + ubbB.w, 0.0f);
      uint4 ho;
      ho.x = pack2(h0, h1); ho.y = pack2(h2, h3);
      ho.z = pack2(h4, h5); ho.w = pack2(h6, h7);
      ((uint4*)hn_out)[(size_t)node * 16 + hl] = ho;
    }
  }
}

// ---------------- the single cooperative kernel ----------------

__global__ __launch_bounds__(256, 4) void mono_kernel(Params P){
  cg::grid_group grid = cg::this_grid();
  __shared__ unsigned short ldsb[128 * 136];   // 34.8 KB -> 4 blocks/CU
  const int GB   = gridDim.x;
  const int tid  = threadIdx.x;
  const int wave = tid >> 6, lane = tid & 63;
  const int quad = lane >> 4, l15 = lane & 15;

  // ---- P0: zero cnt ----
  for (int u = blockIdx.x; u < 196; u += GB){
    int i = u * 256 + tid;
    if (i < N_NODES) P.cnt[i] = 0;
  }
  grid.sync();

  // ---- P1: count (atomics + epos) || cvt W0..W2 -> bf16 Wt^T ----
  {
    const int NU_CNT = 3125, NU_CVT = 192;
    for (int u = blockIdx.x; u < NU_CNT + NU_CVT; u += GB){
      if (u < NU_CNT){
        int e = u * 256 + tid;
        if (e < E_EDGES) P.epos[e] = atomicAdd(&P.cnt[P.edges[E_EDGES + e]], 1);
      } else {
        int idx = (u - NU_CNT) * 256 + tid;        // < 49152
        int w = idx >> 14, r = idx & 16383;
        const float* W = (w == 0) ? P.W0 : (w == 1) ? P.W1 : P.W2;
        P.Wt[w * 16384 + (r & 127) * 128 + (r >> 7)] = (unsigned short)f2bf(W[r]);
      }
    }
  }
  grid.sync();

  // ---- P2: fill ELL || pad ELL || gemm_ln0 (stage Wt0 first) ----
  {
    #pragma unroll
    for (int it = 0; it < 8; ++it){
      int c = tid + it * 256;
      int n = c >> 4, kc = c & 15;
      *(short8*)&ldsb[n * 136 + kc * 8] = *(const short8*)(P.Wt + n * 128 + kc * 8);
    }
    __syncthreads();
    const int NU_FILL = 3125, NU_PAD = 196, NU_G = 782;
    for (int u = blockIdx.x; u < NU_FILL + NU_PAD + NU_G; u += GB){
      if (u < NU_FILL){
        int e = u * 256 + tid;
        if (e < E_EDGES){
          int s = P.edges[e], d = P.edges[E_EDGES + e];
          int pos = P.epos[e];
          if (pos < ELLW){
            float w = rsqrtf((float)(P.cnt[s] + 1)) * rsqrtf((float)(P.cnt[d] + 1));
            int2 pk; pk.x = s; pk.y = __float_as_int(w);
            P.ell[(size_t)d * ELLW + pos] = pk;
          }
        }
      } else if (u < NU_FILL + NU_PAD){
        int i = (u - NU_FILL) * 256 + tid;
        if (i < N_NODES){
          int deg = P.cnt[i];
          int g4 = (i >> 2) << 2;
          int J = max(max(P.cnt[g4], P.cnt[g4 + 1]), max(P.cnt[g4 + 2], P.cnt[g4 + 3]));
          int J4 = min(ELLW, (J + 3) & ~3);
          int2 z; z.x = 0; z.y = 0;
          for (int pp = min(deg, J4); pp < J4; ++pp)
            P.ell[(size_t)i * ELLW + pp] = z;
        }
      } else {
        gemm_ln_tile(P.x, P.lng0, P.lnb0, ldsb, P.yb,
                     (u - NU_FILL - NU_PAD) * 64, wave, quad, l15);
      }
    }
  }
  grid.sync();

  // ---- P3: agg0 (res=x, out->d_out, fused LN1 -> hn) ----
  agg_phase<true, true>(P, P.yb, P.b0, P.x, P.out, P.lng1, P.lnb1, P.hn, GB);
  grid.sync();

  // ---- P4: gemm1 (hn -> yb) ----
  {
    #pragma unroll
    for (int it = 0; it < 8; ++it){
      int c = tid + it * 256;
      int n = c >> 4, kc = c & 15;
      *(short8*)&ldsb[n * 136 + kc * 8] = *(const short8*)(P.Wt + 16384 + n * 128 + kc * 8);
    }
    __syncthreads();
    for (int u = blockIdx.x; u < 782; u += GB)
      gemm_tile(P.hn, ldsb, P.yb, u * 64, wave, quad, l15);
  }
  grid.sync();

  // ---- P5: agg1 (no res, no out, fused LN2 -> hn) ----
  agg_phase<false, true>(P, P.yb, P.b1, nullptr, nullptr, P.lng2, P.lnb2, P.hn, GB);
  grid.sync();

  // ---- P6: gemm2 (hn -> yb) ----
  {
    #pragma unroll
    for (int it = 0; it < 8; ++it){
      int c = tid + it * 256;
      int n = c >> 4, kc = c & 15;
      *(short8*)&ldsb[n * 136 + kc * 8] = *(const short8*)(P.Wt + 32768 + n * 128 + kc * 8);
    }
    __syncthreads();
    for (int u = blockIdx.x; u < 782; u += GB)
      gemm_tile(P.hn, ldsb, P.yb, u * 64, wave, quad, l15);
  }
  grid.sync();

  // ---- P7: agg2 (res=x1 from d_out, out->d_out, no LN) ----
  agg_phase<true, false>(P, P.yb, P.b2, P.out, P.out, nullptr, nullptr, nullptr, GB);
}

// ---------------- launch ----------------

extern "C" void kernel_launch(void* const* d_in, const int* in_sizes, int n_in,
                              void* d_out, int out_size, void* d_ws, size_t ws_size,
                              hipStream_t stream){
  Params P;
  P.x    = (const float*)d_in[0];
  P.edges= (const int*)d_in[1];
  P.lng0 = (const float*)d_in[2];  P.lnb0 = (const float*)d_in[3];
  P.W0   = (const float*)d_in[4];  P.b0   = (const float*)d_in[5];
  P.lng1 = (const float*)d_in[6];  P.lnb1 = (const float*)d_in[7];
  P.W1   = (const float*)d_in[8];  P.b1   = (const float*)d_in[9];
  P.lng2 = (const float*)d_in[10]; P.lnb2 = (const float*)d_in[11];
  P.W2   = (const float*)d_in[12]; P.b2   = (const float*)d_in[13];

  char* p = (char*)d_ws;
  auto carve = [&](size_t bytes) -> void* {
    void* r = (void*)p;
    p += (bytes + 255) & ~(size_t)255;
    return r;
  };
  P.cnt  = (int*)  carve(N_NODES * 4);
  P.epos = (int*)  carve((size_t)E_EDGES * 4);
  P.ell  = (int2*) carve((size_t)N_NODES * ELLW * 8);   // 25.6 MB (pad phase covers read range)
  P.Wt   = (unsigned short*)carve(3 * 128 * 128 * 2);
  P.hn   = (unsigned short*)carve((size_t)N_NODES * 128 * 2);
  P.yb   = (unsigned short*)carve((size_t)N_NODES * 128 * 2);
  P.out  = (float*)d_out;   // doubles as x1 storage (layer-0 residual output)

  // Grid sized to guaranteed co-residency for the cooperative launch.
  int maxb = 0;
  hipError_t oe = hipOccupancyMaxActiveBlocksPerMultiprocessor(&maxb, mono_kernel, 256, 0);
  int ncu = 256;
  int dev = 0;
  hipGetDevice(&dev);
  hipDeviceGetAttribute(&ncu, hipDeviceAttributeMultiprocessorCount, dev);
  int GB = (oe == hipSuccess && maxb > 0) ? maxb * ncu : 2 * ncu;
  if (GB > 3125) GB = 3125;   // never need more units than the largest phase

  void* args[] = { (void*)&P };
  hipLaunchCooperativeKernel(mono_kernel, dim3(GB), dim3(256), args, 0, stream);
}